// Round 21
// baseline (219.339 us; speedup 1.0000x reference)
//
#include <hip/hip_runtime.h>

typedef int i32x4 __attribute__((ext_vector_type(4)));
typedef float f32x4 __attribute__((ext_vector_type(4)));

#define AS1 __attribute__((address_space(1)))
#define AS3 __attribute__((address_space(3)))

#define M_DIM 8192
#define N_DIM 8192
#define K_DIM 2048
#define NT 32   // K-tiles of 64 bytes

// ---------------- fused quantize: x, w (nontemporal read-once loads), prep ----------
// x/w are consumed ONLY here: nontemporal loads keep 256MB of fp32 out of L2 so
// qx/qw (32MB, re-read ~3x by the GEMM) stay resident. (Loads go through a clang
// ext_vector pointer — __builtin_nontemporal_load rejects HIP_vector_type.)
__global__ __launch_bounds__(256) void quant_all_kernel(
    const float* __restrict__ x, const float* __restrict__ w,
    const float* __restrict__ bias,
    const float* __restrict__ in_scale, const float* __restrict__ w_scale,
    const float* __restrict__ b_scale,
    i32x4* __restrict__ qx, i32x4* __restrict__ qw,
    float* __restrict__ oscale, float* __restrict__ obias)
{
    const int bid = blockIdx.x;
    if (bid < 8192) {
        const int idx = (bid & 4095) * 256 + threadIdx.x;   // 0..1048575
        const bool isx = bid < 4096;
        float s = isx ? in_scale[0] : w_scale[idx >> 7];
        const f32x4* p = reinterpret_cast<const f32x4*>(isx ? x : w) + (size_t)idx * 4;
        union { char c[16]; i32x4 v; } u;
#pragma unroll
        for (int v4 = 0; v4 < 4; ++v4) {
            f32x4 f = __builtin_nontemporal_load(p + v4);
            u.c[v4*4+0] = (char)(int)fminf(fmaxf(rintf(f.x / s), -128.f), 127.f);
            u.c[v4*4+1] = (char)(int)fminf(fmaxf(rintf(f.y / s), -128.f), 127.f);
            u.c[v4*4+2] = (char)(int)fminf(fmaxf(rintf(f.z / s), -128.f), 127.f);
            u.c[v4*4+3] = (char)(int)fminf(fmaxf(rintf(f.w / s), -128.f), 127.f);
        }
        (isx ? qx : qw)[idx] = u.v;
    } else {
        const int i = (bid - 8192) * 256 + threadIdx.x;
        if (i < N_DIM) {
            oscale[i] = in_scale[0] * w_scale[i] * 0.5f;   // W_ALPHA
            float bs = b_scale[i];
            float q = fminf(fmaxf(rintf(bias[i] / bs), -128.f), 127.f);
            obias[i] = q * bs * 0.75f;                      // B_BETA
        }
    }
}

// ---------------- int8 GEMM: 128x128 tile, 4 waves of 64x64, 4 blocks/CU ----------------
// FROZEN R19 kernel (175us GEMM; 201us total best): 4-way block independence
// (m114), column-stripe XCD swizzle, R2-verified swizzle (0 conflicts), reads-
// before-stage, no setprio, 2-tile unroll, NONTEMPORAL C-stores (R19: -16us
// total via L2 economy). Schedule-saturated: 6 schedule families all null.
__global__ __launch_bounds__(256, 4) void gemm_i8_kernel(
    const char* __restrict__ qx,   // [M][K] int8
    const char* __restrict__ qw,   // [N][K] int8
    const float* __restrict__ oscale,
    const float* __restrict__ obias,
    float* __restrict__ out)       // [M][N] fp32
{
    __shared__ __align__(16) char ldsA[2 * 8192];
    __shared__ __align__(16) char ldsB[2 * 8192];

    const int t    = threadIdx.x;          // 0..255
    const int lane = t & 63;
    const int wid  = t >> 6;               // 0..3
    const int wm   = wid >> 1;             // 0..1
    const int wn   = wid & 1;              // 0..1

    // XCD column-stripe swizzle (R12/R15-proven locality)
    int bid = blockIdx.x;                   // 4096 blocks
    int sl  = bid >> 3;                     // 0..511
    const size_t brow = (size_t)(sl >> 3) * 128;                    // 64 row-blocks
    const size_t bcol = (size_t)((bid & 7) * 8 + (sl & 7)) * 128;   // 64 col-blocks

    // staging: thread t covers row c*64 + t/4, 16B slot t&3 (linear dest);
    // global source pre-swizzled: logical slot = (t&3) ^ ((t>>3)&3)  (rule 21).
    const int srow  = t >> 2;              // 0..63
    const int lslot = (t & 3) ^ ((t >> 3) & 3);
    const char* gA = qx + (brow + srow) * K_DIM + lslot * 16;
    const char* gB = qw + (bcol + srow) * K_DIM + lslot * 16;
    char* dstA = ldsA + t * 16;
    char* dstB = ldsB + t * 16;

#define STAGE(tt_, bb_) do {                                                              \
    const int ko_ = (tt_) * 64;                                                           \
    __builtin_amdgcn_global_load_lds((const AS1 unsigned int*)(gA + ko_),                 \
        (AS3 unsigned int*)(dstA + (bb_) * 8192), 16, 0, 0);                              \
    __builtin_amdgcn_global_load_lds((const AS1 unsigned int*)(gA + ko_ + 64 * K_DIM),    \
        (AS3 unsigned int*)(dstA + (bb_) * 8192 + 4096), 16, 0, 0);                       \
    __builtin_amdgcn_global_load_lds((const AS1 unsigned int*)(gB + ko_),                 \
        (AS3 unsigned int*)(dstB + (bb_) * 8192), 16, 0, 0);                              \
    __builtin_amdgcn_global_load_lds((const AS1 unsigned int*)(gB + ko_ + 64 * K_DIM),    \
        (AS3 unsigned int*)(dstB + (bb_) * 8192 + 4096), 16, 0, 0);                       \
  } while (0)

    // frag read offsets (swizzled): row r, slot kg ^ ((r>>1)&3); frag step = +1024 B.
    const int lrow = lane & 15;
    const int kg   = lane >> 4;            // 16B k-group 0..3
    const int rA   = wm * 64 + lrow;
    const int rB   = wn * 64 + lrow;
    const int offA0 = rA * 64 + ((kg ^ ((rA >> 1) & 3)) * 16);
    const int offB0 = rB * 64 + ((kg ^ ((rB >> 1) & 3)) * 16);

    i32x4 acc[4][4];
#pragma unroll
    for (int m = 0; m < 4; ++m)
#pragma unroll
        for (int n = 0; n < 4; ++n)
            acc[m][n] = (i32x4){0, 0, 0, 0};

#define MM(m_, n_, a_, b_) acc[m_][n_] = __builtin_amdgcn_mfma_i32_16x16x64_i8((a_), (b_), acc[m_][n_], 0, 0, 0)
#define BAR() do { __builtin_amdgcn_s_barrier(); asm volatile("" ::: "memory"); } while (0)
#define VMCNT0() asm volatile("s_waitcnt vmcnt(0)" ::: "memory")

#define KT(tt_, cb_, PF_) do {                                                            \
    const char* bA = ldsA + (cb_) * 8192;                                                 \
    const char* bB = ldsB + (cb_) * 8192;                                                 \
    i32x4 a0 = *(const i32x4*)(bA + offA0);                                               \
    i32x4 a1 = *(const i32x4*)(bA + offA0 + 1024);                                        \
    i32x4 a2 = *(const i32x4*)(bA + offA0 + 2048);                                        \
    i32x4 a3 = *(const i32x4*)(bA + offA0 + 3072);                                        \
    i32x4 b0 = *(const i32x4*)(bB + offB0);                                               \
    i32x4 b1 = *(const i32x4*)(bB + offB0 + 1024);                                        \
    i32x4 b2 = *(const i32x4*)(bB + offB0 + 2048);                                        \
    i32x4 b3 = *(const i32x4*)(bB + offB0 + 3072);                                        \
    if (PF_) STAGE((tt_) + 1, (cb_) ^ 1);                                                 \
    MM(0,0,a0,b0); MM(0,1,a0,b1); MM(0,2,a0,b2); MM(0,3,a0,b3);                           \
    MM(1,0,a1,b0); MM(1,1,a1,b1); MM(1,2,a1,b2); MM(1,3,a1,b3);                           \
    MM(2,0,a2,b0); MM(2,1,a2,b1); MM(2,2,a2,b2); MM(2,3,a2,b3);                           \
    MM(3,0,a3,b0); MM(3,1,a3,b1); MM(3,2,a3,b2); MM(3,3,a3,b3);                           \
    if (PF_) { VMCNT0(); BAR(); }                                                         \
  } while (0)

    // prologue: tile 0 staged and certified
    STAGE(0, 0);
    VMCNT0();
    BAR();

    for (int it = 0; it < 15; ++it) {      // tiles 0..29
        KT(2*it,     0, 1);
        KT(2*it + 1, 1, 1);
    }
    KT(30, 0, 1);   // stages tile 31
    KT(31, 1, 0);   // final tile, no prefetch/no trailing sync

#undef KT
#undef STAGE
#undef MM
#undef BAR
#undef VMCNT0

    // epilogue: C/D layout col = lane&15, row = (lane>>4)*4 + j. Nontemporal
    // stores (R19 win): C is write-once; keep it out of L2.
    const int colq = lane & 15;
    const int rowq = lane >> 4;
#pragma unroll
    for (int n = 0; n < 4; ++n) {
        size_t col = bcol + wn * 64 + n * 16 + colq;
        float sc = oscale[col];
        float bi = obias[col];
#pragma unroll
        for (int m = 0; m < 4; ++m) {
            size_t rbase = brow + wm * 64 + m * 16 + (size_t)rowq * 4;
#pragma unroll
            for (int j = 0; j < 4; ++j)
                __builtin_nontemporal_store((float)acc[m][n][j] * sc + bi,
                                            &out[(rbase + j) * N_DIM + col]);
        }
    }
}

extern "C" void kernel_launch(void* const* d_in, const int* in_sizes, int n_in,
                              void* d_out, int out_size, void* d_ws, size_t ws_size,
                              hipStream_t stream) {
    const float* x        = (const float*)d_in[0];
    const float* weight   = (const float*)d_in[1];
    const float* bias     = (const float*)d_in[2];
    const float* in_scale = (const float*)d_in[3];
    const float* w_scale  = (const float*)d_in[4];
    const float* b_scale  = (const float*)d_in[5];
    float* out = (float*)d_out;

    char* ws = (char*)d_ws;
    const size_t xk = (size_t)M_DIM * K_DIM;
    const size_t wk = (size_t)N_DIM * K_DIM;
    char*  qx     = ws;
    char*  qw     = ws + xk;
    float* oscale = (float*)(ws + xk + wk);
    float* obias  = oscale + N_DIM;

    quant_all_kernel<<<8224, 256, 0, stream>>>(x, weight, bias, in_scale, w_scale,
                                               b_scale, (i32x4*)qx, (i32x4*)qw,
                                               oscale, obias);
    gemm_i8_kernel<<<4096, 256, 0, stream>>>(qx, qw, oscale, obias, out);
}

// Round 22
// 201.805 us; speedup vs baseline: 1.0869x; 1.0869x over previous
//
#include <hip/hip_runtime.h>

typedef int i32x4 __attribute__((ext_vector_type(4)));

#define AS1 __attribute__((address_space(1)))
#define AS3 __attribute__((address_space(3)))

#define M_DIM 8192
#define N_DIM 8192
#define K_DIM 2048
#define NT 32   // K-tiles of 64 bytes

// ---------------- fused quantize (R16/R19 version — best measured): x, w, prep ----------
// Plain (cached) loads: R21 measured nontemporal x/w loads at -18us total —
// nontemporal STORES of write-once data win (R19), nontemporal LOADS lose.
__global__ __launch_bounds__(256) void quant_all_kernel(
    const float* __restrict__ x, const float* __restrict__ w,
    const float* __restrict__ bias,
    const float* __restrict__ in_scale, const float* __restrict__ w_scale,
    const float* __restrict__ b_scale,
    i32x4* __restrict__ qx, i32x4* __restrict__ qw,
    float* __restrict__ oscale, float* __restrict__ obias)
{
    const int bid = blockIdx.x;
    if (bid < 8192) {
        const int idx = (bid & 4095) * 256 + threadIdx.x;   // 0..1048575
        const bool isx = bid < 4096;
        float s = isx ? in_scale[0] : w_scale[idx >> 7];
        const float4* p = reinterpret_cast<const float4*>(isx ? x : w) + (size_t)idx * 4;
        union { char c[16]; i32x4 v; } u;
#pragma unroll
        for (int v4 = 0; v4 < 4; ++v4) {
            float4 f = p[v4];
            u.c[v4*4+0] = (char)(int)fminf(fmaxf(rintf(f.x / s), -128.f), 127.f);
            u.c[v4*4+1] = (char)(int)fminf(fmaxf(rintf(f.y / s), -128.f), 127.f);
            u.c[v4*4+2] = (char)(int)fminf(fmaxf(rintf(f.z / s), -128.f), 127.f);
            u.c[v4*4+3] = (char)(int)fminf(fmaxf(rintf(f.w / s), -128.f), 127.f);
        }
        (isx ? qx : qw)[idx] = u.v;
    } else {
        const int i = (bid - 8192) * 256 + threadIdx.x;
        if (i < N_DIM) {
            oscale[i] = in_scale[0] * w_scale[i] * 0.5f;   // W_ALPHA
            float bs = b_scale[i];
            float q = fminf(fmaxf(rintf(bias[i] / bs), -128.f), 127.f);
            obias[i] = q * bs * 0.75f;                      // B_BETA
        }
    }
}

// ---------------- int8 GEMM: 128x128 tile, 4 waves of 64x64, 4 blocks/CU ----------------
// FROZEN R19 kernel (175us GEMM; 201us total best): 4-way block independence
// (m114), column-stripe XCD swizzle, R2-verified swizzle (0 conflicts), reads-
// before-stage, no setprio, 2-tile unroll, NONTEMPORAL C-stores (R19: -16us
// total via L2 economy). Schedule-saturated: 6 schedule families all null.
__global__ __launch_bounds__(256, 4) void gemm_i8_kernel(
    const char* __restrict__ qx,   // [M][K] int8
    const char* __restrict__ qw,   // [N][K] int8
    const float* __restrict__ oscale,
    const float* __restrict__ obias,
    float* __restrict__ out)       // [M][N] fp32
{
    __shared__ __align__(16) char ldsA[2 * 8192];
    __shared__ __align__(16) char ldsB[2 * 8192];

    const int t    = threadIdx.x;          // 0..255
    const int lane = t & 63;
    const int wid  = t >> 6;               // 0..3
    const int wm   = wid >> 1;             // 0..1
    const int wn   = wid & 1;              // 0..1

    // XCD column-stripe swizzle (R12/R15-proven locality)
    int bid = blockIdx.x;                   // 4096 blocks
    int sl  = bid >> 3;                     // 0..511
    const size_t brow = (size_t)(sl >> 3) * 128;                    // 64 row-blocks
    const size_t bcol = (size_t)((bid & 7) * 8 + (sl & 7)) * 128;   // 64 col-blocks

    // staging: thread t covers row c*64 + t/4, 16B slot t&3 (linear dest);
    // global source pre-swizzled: logical slot = (t&3) ^ ((t>>3)&3)  (rule 21).
    const int srow  = t >> 2;              // 0..63
    const int lslot = (t & 3) ^ ((t >> 3) & 3);
    const char* gA = qx + (brow + srow) * K_DIM + lslot * 16;
    const char* gB = qw + (bcol + srow) * K_DIM + lslot * 16;
    char* dstA = ldsA + t * 16;
    char* dstB = ldsB + t * 16;

#define STAGE(tt_, bb_) do {                                                              \
    const int ko_ = (tt_) * 64;                                                           \
    __builtin_amdgcn_global_load_lds((const AS1 unsigned int*)(gA + ko_),                 \
        (AS3 unsigned int*)(dstA + (bb_) * 8192), 16, 0, 0);                              \
    __builtin_amdgcn_global_load_lds((const AS1 unsigned int*)(gA + ko_ + 64 * K_DIM),    \
        (AS3 unsigned int*)(dstA + (bb_) * 8192 + 4096), 16, 0, 0);                       \
    __builtin_amdgcn_global_load_lds((const AS1 unsigned int*)(gB + ko_),                 \
        (AS3 unsigned int*)(dstB + (bb_) * 8192), 16, 0, 0);                              \
    __builtin_amdgcn_global_load_lds((const AS1 unsigned int*)(gB + ko_ + 64 * K_DIM),    \
        (AS3 unsigned int*)(dstB + (bb_) * 8192 + 4096), 16, 0, 0);                       \
  } while (0)

    // frag read offsets (swizzled): row r, slot kg ^ ((r>>1)&3); frag step = +1024 B.
    const int lrow = lane & 15;
    const int kg   = lane >> 4;            // 16B k-group 0..3
    const int rA   = wm * 64 + lrow;
    const int rB   = wn * 64 + lrow;
    const int offA0 = rA * 64 + ((kg ^ ((rA >> 1) & 3)) * 16);
    const int offB0 = rB * 64 + ((kg ^ ((rB >> 1) & 3)) * 16);

    i32x4 acc[4][4];
#pragma unroll
    for (int m = 0; m < 4; ++m)
#pragma unroll
        for (int n = 0; n < 4; ++n)
            acc[m][n] = (i32x4){0, 0, 0, 0};

#define MM(m_, n_, a_, b_) acc[m_][n_] = __builtin_amdgcn_mfma_i32_16x16x64_i8((a_), (b_), acc[m_][n_], 0, 0, 0)
#define BAR() do { __builtin_amdgcn_s_barrier(); asm volatile("" ::: "memory"); } while (0)
#define VMCNT0() asm volatile("s_waitcnt vmcnt(0)" ::: "memory")

#define KT(tt_, cb_, PF_) do {                                                            \
    const char* bA = ldsA + (cb_) * 8192;                                                 \
    const char* bB = ldsB + (cb_) * 8192;                                                 \
    i32x4 a0 = *(const i32x4*)(bA + offA0);                                               \
    i32x4 a1 = *(const i32x4*)(bA + offA0 + 1024);                                        \
    i32x4 a2 = *(const i32x4*)(bA + offA0 + 2048);                                        \
    i32x4 a3 = *(const i32x4*)(bA + offA0 + 3072);                                        \
    i32x4 b0 = *(const i32x4*)(bB + offB0);                                               \
    i32x4 b1 = *(const i32x4*)(bB + offB0 + 1024);                                        \
    i32x4 b2 = *(const i32x4*)(bB + offB0 + 2048);                                        \
    i32x4 b3 = *(const i32x4*)(bB + offB0 + 3072);                                        \
    if (PF_) STAGE((tt_) + 1, (cb_) ^ 1);                                                 \
    MM(0,0,a0,b0); MM(0,1,a0,b1); MM(0,2,a0,b2); MM(0,3,a0,b3);                           \
    MM(1,0,a1,b0); MM(1,1,a1,b1); MM(1,2,a1,b2); MM(1,3,a1,b3);                           \
    MM(2,0,a2,b0); MM(2,1,a2,b1); MM(2,2,a2,b2); MM(2,3,a2,b3);                           \
    MM(3,0,a3,b0); MM(3,1,a3,b1); MM(3,2,a3,b2); MM(3,3,a3,b3);                           \
    if (PF_) { VMCNT0(); BAR(); }                                                         \
  } while (0)

    // prologue: tile 0 staged and certified
    STAGE(0, 0);
    VMCNT0();
    BAR();

    for (int it = 0; it < 15; ++it) {      // tiles 0..29
        KT(2*it,     0, 1);
        KT(2*it + 1, 1, 1);
    }
    KT(30, 0, 1);   // stages tile 31
    KT(31, 1, 0);   // final tile, no prefetch/no trailing sync

#undef KT
#undef STAGE
#undef MM
#undef BAR
#undef VMCNT0

    // epilogue: C/D layout col = lane&15, row = (lane>>4)*4 + j. Nontemporal
    // stores (R19 win): C is write-once; keep it out of L2.
    const int colq = lane & 15;
    const int rowq = lane >> 4;
#pragma unroll
    for (int n = 0; n < 4; ++n) {
        size_t col = bcol + wn * 64 + n * 16 + colq;
        float sc = oscale[col];
        float bi = obias[col];
#pragma unroll
        for (int m = 0; m < 4; ++m) {
            size_t rbase = brow + wm * 64 + m * 16 + (size_t)rowq * 4;
#pragma unroll
            for (int j = 0; j < 4; ++j)
                __builtin_nontemporal_store((float)acc[m][n][j] * sc + bi,
                                            &out[(rbase + j) * N_DIM + col]);
        }
    }
}

extern "C" void kernel_launch(void* const* d_in, const int* in_sizes, int n_in,
                              void* d_out, int out_size, void* d_ws, size_t ws_size,
                              hipStream_t stream) {
    const float* x        = (const float*)d_in[0];
    const float* weight   = (const float*)d_in[1];
    const float* bias     = (const float*)d_in[2];
    const float* in_scale = (const float*)d_in[3];
    const float* w_scale  = (const float*)d_in[4];
    const float* b_scale  = (const float*)d_in[5];
    float* out = (float*)d_out;

    char* ws = (char*)d_ws;
    const size_t xk = (size_t)M_DIM * K_DIM;
    const size_t wk = (size_t)N_DIM * K_DIM;
    char*  qx     = ws;
    char*  qw     = ws + xk;
    float* oscale = (float*)(ws + xk + wk);
    float* obias  = oscale + N_DIM;

    quant_all_kernel<<<8224, 256, 0, stream>>>(x, weight, bias, in_scale, w_scale,
                                               b_scale, (i32x4*)qx, (i32x4*)qw,
                                               oscale, obias);
    gemm_i8_kernel<<<4096, 256, 0, stream>>>(qx, qw, oscale, obias, out);
}